// Round 17
// baseline (154.095 us; speedup 1.0000x reference)
//
#include <hip/hip_runtime.h>
#include <hip/hip_bf16.h>

#define SL 2048
#define NH 16
#define HD 128
#define EMB 2048

typedef __attribute__((ext_vector_type(8))) __bf16 bf16x8;
typedef __attribute__((ext_vector_type(4))) float f32x4;
typedef __attribute__((ext_vector_type(8))) short short8;

__device__ __forceinline__ short bf16bits(float x) {
  union { __hip_bfloat16 h; short s; } u;
  u.h = __float2bfloat16(x);
  return u.s;
}

__device__ __forceinline__ float fexp2(float x) {   // native v_exp_f32 (2^x)
  return __builtin_amdgcn_exp2f(x);
}

#define GLDS16(gp, lp) __builtin_amdgcn_global_load_lds( \
    (__attribute__((address_space(1))) void*)(gp), \
    (__attribute__((address_space(3))) void*)(lp), 16, 0, 0)

// ---------------- merged cast: x row-major; Wq,Wo CHUNK-MAJOR [k/8][col][8k];
// Wv row-major (for gemm64v staging).
__global__ __launch_bounds__(256) void cast_all(const float* __restrict__ x,
                                                const float* __restrict__ Wq,
                                                const float* __restrict__ Wv,
                                                const float* __restrict__ Wo,
                                                short* __restrict__ xb,
                                                short* __restrict__ wqc,
                                                short* __restrict__ wvb,
                                                short* __restrict__ woc) {
  long i = ((long)blockIdx.x * 256 + threadIdx.x) * 8;   // 12845056 elements total
  const float* in; short* out; long off; int ck = 0;
  if (i < 4194304)      { in = x;  out = xb;  off = i; }
  else if (i < 8388608) { in = Wq; out = wqc; off = i - 4194304; ck = 1; }
  else if (i < 8650752) { in = Wv; out = wvb; off = i - 8388608; }
  else                  { in = Wo; out = woc; off = i - 8650752; ck = 1; }
  float4 a = *(const float4*)(in + off);
  float4 b = *(const float4*)(in + off + 4);
  short8 o;
  o[0] = bf16bits(a.x); o[1] = bf16bits(a.y); o[2] = bf16bits(a.z); o[3] = bf16bits(a.w);
  o[4] = bf16bits(b.x); o[5] = bf16bits(b.y); o[6] = bf16bits(b.z); o[7] = bf16bits(b.w);
  long dst = off;
  if (ck) {                      // (col,k) -> ((k>>3)*2048 + col)*8 + (k&7)
    long col = off >> 11, k0 = off & 2047;
    dst = ((k0 >> 3) * 2048 + col) * 8;
  }
  *(short8*)(out + dst) = o;
}

// ------- 128x128 tile, BK=64, 16-wave NT GEMM; A via LDS (4-deep glds pipeline),
// B DIRECT from chunk-major global (L1-served; off the LDS pipe).
// LDS/iter: A-read 65.5 KB + A-write 16 KB (vs 160 KB when B was LDS-staged).
// MODE 0: C f32. MODE 1: fused rmsnorm+rope(Q)+rope(rope(Q)); Qb pre-scaled
// by 1/sqrt(128)*log2(e) (exp2-domain attn).
template<int MODE>
__global__ __launch_bounds__(1024, 1) void gemm128(const short* __restrict__ A,
                                                   const short* __restrict__ Bc,
                                                   float* __restrict__ C,
                                                   short* __restrict__ Qb,
                                                   short* __restrict__ Kb,
                                                   const float* __restrict__ cosT,
                                                   const float* __restrict__ sinT,
                                                   const float* __restrict__ gamma) {
  __shared__ short As[4 * 8192];            // 4 bufs x 16 KB (A tile [128][64])
  __shared__ float xch[16384];              // MODE1 exchange [128][128]
  __shared__ float ssb[512];                // MODE1 row sums [4][128]
  const int K = 2048;
  int id = blockIdx.x;                      // 256 blocks
  int nid = (id & 7) * 32 + (id >> 3);      // bijective XCD swizzle
  int tn = nid >> 4, tm = nid & 15;
  int tid = threadIdx.x;
  int w = tid >> 6, lane = tid & 63;
  int g = lane >> 4, c = lane & 15;
  int wr = w >> 2, wc = w & 3;              // 4M x 4N wave grid (32x32 per wave)
  const short* Ab = A + (long)(tm * 128) * K;
  int lr = lane >> 3;
  int lsw = (lane & 7) ^ lr;                // pre-swizzled source chunk
  int bcol = tn * 128 + wc * 32 + c;        // this lane's B column base
  f32x4 zero = {0.f, 0.f, 0.f, 0.f};
  f32x4 acc[2][2];
#pragma unroll
  for (int m = 0; m < 2; ++m)
#pragma unroll
    for (int n = 0; n < 2; ++n) acc[m][n] = zero;

  // 1 glds per wave per tile: wave w stages rows w*8..w*8+7
#define STG(buf, kt) GLDS16(Ab + (long)(w * 8 + lr) * K + (kt) + lsw * 8, \
                            As + (buf) * 8192 + w * 512)
  // B frags for K-tile t (4 coalesced 16B loads, L1-served)
#define LOADB(dst, t) do { \
    int chb = (t) * 8; \
    _Pragma("unroll") \
    for (int kk2 = 0; kk2 < 2; ++kk2) \
      _Pragma("unroll") \
      for (int n2 = 0; n2 < 2; ++n2) \
        dst[kk2][n2] = *(const bf16x8*)(Bc + \
            ((long)(chb + kk2 * 4 + g) * 2048 + bcol + n2 * 16) * 8); \
    } while (0)
  // compute K-tile t from LDS buf + B regs
#define COMP(t, bfr) do { \
    const short* Ax = As + ((t) & 3) * 8192; \
    bf16x8 af[2][2]; \
    _Pragma("unroll") \
    for (int kk2 = 0; kk2 < 2; ++kk2) { \
      int ch = ((kk2 * 4 + g) ^ (c & 7)) * 8; \
      _Pragma("unroll") \
      for (int m2 = 0; m2 < 2; ++m2) \
        af[kk2][m2] = *(const bf16x8*)(Ax + (wr * 32 + m2 * 16 + c) * 64 + ch); \
    } \
    __builtin_amdgcn_s_setprio(1); \
    _Pragma("unroll") \
    for (int kk2 = 0; kk2 < 2; ++kk2) \
      _Pragma("unroll") \
      for (int m2 = 0; m2 < 2; ++m2) \
        _Pragma("unroll") \
        for (int n2 = 0; n2 < 2; ++n2) \
          acc[m2][n2] = __builtin_amdgcn_mfma_f32_16x16x32_bf16(af[kk2][m2], \
                            bfr[kk2][n2], acc[m2][n2], 0, 0, 0); \
    __builtin_amdgcn_s_setprio(0); \
  } while (0)

  bf16x8 bfrA[2][2], bfrB[2][2];
  STG(0, 0);
  STG(1, 64);
  STG(2, 128);
  LOADB(bfrA, 0);
  asm volatile("s_waitcnt vmcnt(6)" ::: "memory");   // g0 done (g1,g2,B0x4 fly)
  __builtin_amdgcn_s_barrier();

  for (int bt = 0; bt < 16; ++bt) {
    int t0 = bt * 2, t1 = t0 + 1;
    // even sub-iter: consume bfrA, prefetch bfrB
    if (t0 <= 28) STG((t0 + 3) & 3, (t0 + 3) * 64);
    LOADB(bfrB, t0 + 1);
    COMP(t0, bfrA);
    if (t0 <= 28) asm volatile("s_waitcnt vmcnt(6)" ::: "memory");
    else          asm volatile("s_waitcnt vmcnt(4)" ::: "memory");
    __builtin_amdgcn_s_barrier();
    // odd sub-iter: consume bfrB, prefetch bfrA
    if (t1 <= 28) STG((t1 + 3) & 3, (t1 + 3) * 64);
    if (t1 < 31) LOADB(bfrA, t1 + 1);
    COMP(t1, bfrB);
    if (t1 < 31) {
      if (t1 <= 28) asm volatile("s_waitcnt vmcnt(6)" ::: "memory");
      else          asm volatile("s_waitcnt vmcnt(4)" ::: "memory");
      __builtin_amdgcn_s_barrier();
    }
  }
#undef STG
#undef LOADB
#undef COMP

  if constexpr (MODE == 0) {
#pragma unroll
    for (int m = 0; m < 2; ++m)
#pragma unroll
      for (int n = 0; n < 2; ++n)
#pragma unroll
        for (int r = 0; r < 4; ++r) {
          int row = tm * 128 + wr * 32 + m * 16 + g * 4 + r;
          int col = tn * 128 + wc * 32 + n * 16 + c;
          C[(long)row * 2048 + col] = acc[m][n][r];
        }
  } else {
    // fused rmsnorm + rope(Q) + rope(rope(Q)); head = tn, d = wc*32+n*16+c.
    float ssmr[2][4];
#pragma unroll
    for (int m = 0; m < 2; ++m)
#pragma unroll
      for (int r = 0; r < 4; ++r) {
        float s = acc[m][0][r] * acc[m][0][r] + acc[m][1][r] * acc[m][1][r];
#pragma unroll
        for (int off = 1; off <= 8; off <<= 1) s += __shfl_xor(s, off, 64);
        ssmr[m][r] = s;                      // sum over this wave's 32 cols
      }
    if (c == 0) {
#pragma unroll
      for (int m = 0; m < 2; ++m)
#pragma unroll
        for (int r = 0; r < 4; ++r)
          ssb[wc * 128 + wr * 32 + m * 16 + g * 4 + r] = ssmr[m][r];
    }
#pragma unroll
    for (int m = 0; m < 2; ++m)
#pragma unroll
      for (int n = 0; n < 2; ++n)
#pragma unroll
        for (int r = 0; r < 4; ++r)
          xch[(wr * 32 + m * 16 + g * 4 + r) * 128 + wc * 32 + n * 16 + c] = acc[m][n][r];
    __syncthreads();
    float rn[2][4];
#pragma unroll
    for (int m = 0; m < 2; ++m)
#pragma unroll
      for (int r = 0; r < 4; ++r) {
        int rl = wr * 32 + m * 16 + g * 4 + r;
        float s4 = ssb[rl] + ssb[128 + rl] + ssb[256 + rl] + ssb[384 + rl];
        rn[m][r] = rsqrtf(s4 * (1.0f / 128.0f) + 1e-6f);
      }
    float sgn = (wc < 2) ? -1.f : 1.f;
    float g_own[2], g_par[2];
#pragma unroll
    for (int n = 0; n < 2; ++n) {
      int d = wc * 32 + n * 16 + c;
      g_own[n] = gamma[d];
      g_par[n] = gamma[d ^ 64];
    }
    const float QSC = 0.08838834764831845f * 1.4426950408889634f;  // sc * log2(e)
#pragma unroll
    for (int m = 0; m < 2; ++m)
#pragma unroll
      for (int n = 0; n < 2; ++n)
#pragma unroll
        for (int r = 0; r < 4; ++r) {
          int rl = wr * 32 + m * 16 + g * 4 + r;
          int s = tm * 128 + rl;
          int d = wc * 32 + n * 16 + c;
          int u = (wc & 1) * 32 + n * 16 + c;       // d mod 64 (tables 64-periodic)
          float cv = cosT[s * 128 + u];
          float sv = sinT[s * 128 + u];
          float xo = acc[m][n][r] * rn[m][r] * g_own[n];
          float xq = xch[rl * 128 + (d ^ 64)] * rn[m][r] * g_par[n];
          float y  = xo * cv + sgn * xq * sv;       // rope(Q)
          float yp = xq * cv - sgn * xo * sv;       // rope(Q) at partner d
          float kk = y * cv + sgn * yp * sv;        // rope(rope(Q)) (source bug)
          long o = ((long)tn * SL + s) * HD + d;
          Qb[o] = bf16bits(y * QSC);                // pre-scaled for exp2 attn
          Kb[o] = bf16bits(kk);                     // K unscaled
        }
  }
}

// ----------------------- TRIPLE-buffered NT GEMM 64x128 (proven), V^T only.
// A = xb row-major, B = wvb row-major [128][2048].
__global__ __launch_bounds__(256, 3) void gemm64v(const short* __restrict__ A,
                                                  const short* __restrict__ B,
                                                  short* __restrict__ VT) {
  __shared__ char lds_raw[36864];
  short* As = (short*)lds_raw;             // [3][64*32]  12 KB
  short* Bs = (short*)(lds_raw + 12288);   // [3][128*32] 24 KB
  const int K = 2048;
  int nwg = gridDim.x;                          // 32
  int id = blockIdx.x;
  int nid = (id & 7) * (nwg >> 3) + (id >> 3);
  int tm = nid & 31;
  int tid = threadIdx.x;
  int wave = tid >> 6, lane = tid & 63;
  int g = lane >> 4, c = lane & 15;
  int wr = wave >> 1, wc = wave & 1;
  const short* Ab = A + (long)(tm * 64) * K;
  const short* Bb = B;                          // Wv rows 0..127
  int swz = (lane & 3) ^ ((lane >> 3) & 3);
  int rdc = (g ^ ((c >> 1) & 3)) * 8;
  f32x4 zero = {0.f, 0.f, 0.f, 0.f};
  f32x4 acc[2][4];
#pragma unroll
  for (int m = 0; m < 2; ++m)
#pragma unroll
    for (int n = 0; n < 4; ++n) acc[m][n] = zero;

#define STG(buf, kt) do { \
    GLDS16(Ab + (long)(wave * 16 + (lane >> 2)) * K + (kt) + swz * 8, \
           As + (buf) * 2048 + wave * 512); \
    _Pragma("unroll") \
    for (int hh = 0; hh < 2; ++hh) { \
      int rb = wave * 32 + hh * 16; \
      GLDS16(Bb + (long)(rb + (lane >> 2)) * K + (kt) + swz * 8, \
             Bs + (buf) * 4096 + rb * 32); \
    } } while (0)

  STG(0, 0);
  STG(1, 32);
  asm volatile("s_waitcnt vmcnt(3)" ::: "memory");
  __builtin_amdgcn_s_barrier();

  int b0 = 0, b1 = 1, b2 = 2;
  for (int it = 0; it < 64; ++it) {
    if (it < 62) STG(b2, (it + 2) * 32);
    bf16x8 a[2], b[4];
#pragma unroll
    for (int m = 0; m < 2; ++m)
      a[m] = *(const bf16x8*)(As + b0 * 2048 + (wr * 32 + m * 16 + c) * 32 + rdc);
#pragma unroll
    for (int n = 0; n < 4; ++n)
      b[n] = *(const bf16x8*)(Bs + b0 * 4096 + (wc * 64 + n * 16 + c) * 32 + rdc);
    __builtin_amdgcn_s_setprio(1);
#pragma unroll
    for (int m = 0; m < 2; ++m)
#pragma unroll
      for (int n = 0; n < 4; ++n)
        acc[m][n] = __builtin_amdgcn_mfma_f32_16x16x32_bf16(a[m], b[n], acc[m][n], 0, 0, 0);
    __builtin_amdgcn_s_setprio(0);
    if (it < 62) {
      asm volatile("s_waitcnt vmcnt(3)" ::: "memory");
      __builtin_amdgcn_s_barrier();
    } else if (it == 62) {
      asm volatile("s_waitcnt vmcnt(0)" ::: "memory");
      __builtin_amdgcn_s_barrier();
    }
    int t = b0; b0 = b1; b1 = b2; b2 = t;
  }
#undef STG

#pragma unroll
  for (int m = 0; m < 2; ++m)
#pragma unroll
    for (int n = 0; n < 4; ++n)
#pragma unroll
      for (int r = 0; r < 4; ++r) {
        int s = tm * 64 + wr * 32 + m * 16 + g * 4 + r;
        int d = wc * 64 + n * 16 + c;
        VT[(long)d * SL + s] = bf16bits(acc[m][n][r]);
      }
}

// ------------------------------------------- causal flash attention, k-split chunks
// (r16-proven: head-pinned XCD decode, exp2-domain native, packed b64 Ps stores)
__global__ __launch_bounds__(256, 2) void attn_part(const short* __restrict__ Qb,
                                                    const short* __restrict__ Kb,
                                                    const short* __restrict__ VTg,
                                                    short* __restrict__ att,
                                                    float* __restrict__ pO,
                                                    float* __restrict__ pml) {
  __shared__ short Ks[2][64 * 128];   // 32 KB
  __shared__ short Vs[2][128 * 64];   // 32 KB
  __shared__ short Ps[4][16 * 72];    // 9 KB per-wave
  int wave = threadIdx.x >> 6, lane = threadIdx.x & 63;
  int g = lane >> 4, c = lane & 15;
  int id = blockIdx.x;
  int h = ((id & 7) << 1) | (id >> 8);   // head-pinned XCD decode
  int x = (id >> 3) & 15;
  int cbk = (id >> 7) & 1;
  const short* Qh = Qb + (long)h * SL * HD;
  const short* Kh = Kb + (long)h * SL * HD;
  f32x4 zero = {0.f, 0.f, 0.f, 0.f};
  const float THR2 = 11.541560327111707f;   // 8 * log2(e)

  int pqt[2], plo[2], pcnt[2], pout[2];
  if (cbk == 0) {
    pqt[0] = x;      plo[0] = 0;      pcnt[0] = x + 1;  pout[0] = 0;
    pqt[1] = 31 - x; plo[1] = 0;      pcnt[1] = 16 - x; pout[1] = 1;
  } else {
    pqt[0] = 31 - x; plo[0] = 16 - x; pcnt[0] = 16;     pout[0] = 2;
    pqt[1] = 0;      plo[1] = 0;      pcnt[1] = 0;      pout[1] = 0;
  }
  int total = pcnt[0] + pcnt[1];

#define ASTAGE(b, kvb) do { \
    _Pragma("unroll") \
    for (int i = 0; i < 4; ++i) { \
      int rb = wave * 16 + i * 4; \
      int row = rb + (lane >> 4); \
      int c16 = (lane & 15) ^ (row & 7); \
      GLDS16(Kh + (long)((kvb) + row) * HD + c16 * 8, &Ks[b][rb * 128]); \
    } \
    _Pragma("unroll") \
    for (int i = 0; i < 4; ++i) { \
      int dbase = i * 32 + wave * 8; \
      int drow = dbase + (lane >> 3); \
      int u8 = (lane & 7) ^ (drow & 7); \
      GLDS16(VTg + (long)drow * SL + (kvb) + u8 * 8, &Vs[b][dbase * 64]); \
    } } while (0)

  ASTAGE(0, plo[0] * 64);
  int s = 0;

  for (int p = 0; p < 2; ++p) {
    int nt = pcnt[p];
    if (nt == 0) break;
    int qt = pqt[p];
    int qb = qt * 64 + wave * 16;
    int qown = qb + c;

    bf16x8 aq[4];
#pragma unroll
    for (int kc = 0; kc < 4; ++kc)
      aq[kc] = *(const bf16x8*)(Qh + (long)qown * HD + kc * 32 + g * 8);

    float m = -1e30f, l = 0.f;
    f32x4 O[8];
#pragma unroll
    for (int d8 = 0; d8 < 8; ++d8) O[d8] = zero;

    for (int i = 0; i < nt; ++i, ++s) {
      int kt = plo[p] + i;
      int kvb = kt * 64;
      int bcu = s & 1;
      asm volatile("s_waitcnt vmcnt(0)" ::: "memory");
      __builtin_amdgcn_s_barrier();
      {
        int ns = s + 1;
        if (ns < total) {
          int np = (ns < pcnt[0]) ? 0 : 1;
          int nkt = plo[np] + (ns - (np ? pcnt[0] : 0));
          ASTAGE(bcu ^ 1, nkt * 64);
        }
      }

      f32x4 sf[4];
#pragma unroll
      for (int n = 0; n < 4; ++n) sf[n] = zero;
      __builtin_amdgcn_s_setprio(1);
#pragma unroll
      for (int kc = 0; kc < 4; ++kc)
#pragma unroll
        for (int n = 0; n < 4; ++n) {
          int row = n * 16 + c;
          int u = (kc * 4 + g) ^ (row & 7);
          bf16x8 bk = *(const bf16x8*)(&Ks[bcu][row * 128 + u * 8]);
          sf[n] = __builtin_amdgcn_mfma_f32_16x16x32_bf16(bk, aq[kc], sf[n], 0, 0, 0);
        }
      __builtin_amdgcn_s_setprio(0);

      float pm = -1e30f;
      if (kt == qt) {
#pragma unroll
        for (int n = 0; n < 4; ++n) {
#pragma unroll
          for (int r = 0; r < 4; ++r) {
            int k = kvb + n * 16 + g * 4 + r;
            if (k > qown) sf[n][r] = -1e30f;
          }
          float a0 = fmaxf(sf[n][0], sf[n][1]);
          float a1 = fmaxf(sf[n][2], sf[n][3]);
          pm = fmaxf(pm, fmaxf(a0, a1));
        }
      } else {
#pragma unroll
        for (int n = 0; n < 4; ++n) {
          float a0 = fmaxf(sf[n][0], sf[n][1]);
          float a1 = fmaxf(sf[n][2], sf[n][3]);
          pm = fmaxf(pm, fmaxf(a0, a1));
        }
      }
      pm = fmaxf(pm, __shfl_xor(pm, 16, 64));
      pm = fmaxf(pm, __shfl_xor(pm, 32, 64));

      if (__any(pm > m + THR2)) {
        float mn_ = fmaxf(m, pm);
        float corr = fexp2(m - mn_);
        m = mn_;
        l *= corr;
        float c4[4];
#pragma unroll
        for (int r = 0; r < 4; ++r) c4[r] = __shfl(corr, g * 4 + r, 64);
#pragma unroll
        for (int d8 = 0; d8 < 8; ++d8)
#pragma unroll
          for (int r = 0; r < 4; ++r) O[d8][r] *= c4[r];
      }

#pragma unroll
      for (int n = 0; n < 4; ++n) {
        float p0 = fexp2(sf[n][0] - m);
        float p1 = fexp2(sf[n][1] - m);
        float p2 = fexp2(sf[n][2] - m);
        float p3 = fexp2(sf[n][3] - m);
        l += (p0 + p1) + (p2 + p3);
        unsigned lo = (unsigned)(unsigned short)bf16bits(p0) |
                      ((unsigned)(unsigned short)bf16bits(p1) << 16);
        unsigned hi = (unsigned)(unsigned short)bf16bits(p2) |
                      ((unsigned)(unsigned short)bf16bits(p3) << 16);
        unsigned long long pq = (unsigned long long)lo | ((unsigned long long)hi << 32);
        *(unsigned long long*)&Ps[wave][c * 72 + n * 16 + g * 4] = pq;
      }

#pragma unroll
      for (int k2 = 0; k2 < 2; ++k2) {
        bf16x8 ap = *(const bf16x8*)(&Ps[wave][c * 72 + k2 * 32 + g * 8]);
        __builtin_amdgcn_s_setprio(1);
#pragma unroll
        for (int d8 = 0; d8 < 8; ++d8) {
          int drow = d8 * 16 + c;
          int u = (k2 * 4 + g) ^ (c & 7);
          bf16x8 bv = *(const bf16x8*)(&Vs[bcu][drow * 64 + u * 8]);
          O[d8] = __builtin_amdgcn_mfma_f32_16x16x32_bf16(ap, bv, O[d8], 0, 0, 0);
        }
        __builtin_amdgcn_s_setprio(0);
      }
    }

    if (pout[p] == 0) {
      float lf = l;
      lf += __shfl_xor(lf, 16, 64);
      lf += __shfl_xor(lf, 32, 64);
      float rinv = 1.0f / lf;
      float r4[4];
#pragma unroll
      for (int r = 0; r < 4; ++r) r4[r] = __shfl(rinv, g * 4 + r, 64);
#pragma unroll
      for (int d8 = 0; d8 < 8; ++d8)
#pragma unroll
        for (int r = 0; r < 4; ++r) {
          int q = qb + g * 4 + r;
          att[(long)q * EMB + h * HD + d8 * 16 + c] = bf16bits(O[d8][r] * r4[r]);
        }
    } else {
      int part = pout[p] - 1;
      float lf = l;
      lf += __shfl_xor(lf, 16, 64);
      lf += __shfl_xor(lf, 32, 64);
      float* Op = pO + ((long)(part * 16 + x) * 16 + h) * 8192;
#pragma unroll
      for (int d8 = 0; d8 < 8; ++d8)
#pragma unroll
        for (int r = 0; r < 4; ++r)
          Op[(wave * 16 + g * 4 + r) * 128 + d8 * 16 + c] = O[d8][r];
      if (g == 0) {
        float* pmb = pml + ((part * 16 + x) * 16 + h) * 64 + wave * 16 + c;
        pmb[0]     = m;     // log2-domain running max
        pmb[32768] = lf;
      }
    }
  }
#undef ASTAGE
}

// ------------------------------------------- combine the two partials (long strips)
__global__ __launch_bounds__(256) void attn_comb(const float* __restrict__ pO,
                                                 const float* __restrict__ pml,
                                                 short* __restrict__ att) {
  int b = blockIdx.x;
  int x = b & 15, h = b >> 4;
  int qt = 31 - x;
  int t = threadIdx.x;
  int q = t >> 2, d0 = (t & 3) * 32;
  int i0 = (x * 16 + h) * 64 + q;
  int i1 = (256 + x * 16 + h) * 64 + q;
  float m0 = pml[i0], m1 = pml[i1];
  float l0 = pml[32768 + i0], l1 = pml[32768 + i1];
  float M = fmaxf(m0, m1);
  float w0 = __builtin_amdgcn_exp2f(m0 - M), w1 = __builtin_amdgcn_exp2f(m1 - M);
  float inv = 1.0f / (l0 * w0 + l1 * w1);
  const float* O0 = pO + ((long)(x * 16 + h)) * 8192 + q * 128 + d0;
  const float* O1 = pO + ((long)(256 + x * 16 + h)) * 8192 + q * 128 + d0;
  short* out = att + (long)(qt * 64 + q) * EMB + h * HD + d0;
#pragma unroll
  for (int j = 0; j < 32; j += 4) {
    float4 a = *(const float4*)(O0 + j);
    float4 bb = *(const float4*)(O1 + j);
    out[j + 0] = bf16bits((a.x * w0 + bb.x * w1) * inv);
    out[j + 1] = bf16bits((a.y * w0 + bb.y * w1) * inv);
    out[j + 2] = bf16bits((a.z * w0 + bb.z * w1) * inv);
    out[j + 3] = bf16bits((a.w * w0 + bb.w * w1) * inv);
  }
}

// ---------------------------------------------------------------------- launch
extern "C" void kernel_launch(void* const* d_in, const int* in_sizes, int n_in,
                              void* d_out, int out_size, void* d_ws, size_t ws_size,
                              hipStream_t stream) {
  const float* x    = (const float*)d_in[0];
  const float* cosT = (const float*)d_in[1];
  const float* sinT = (const float*)d_in[2];
  const float* Wq   = (const float*)d_in[3];
  const float* Wv   = (const float*)d_in[5];
  const float* Wo   = (const float*)d_in[6];
  const float* qg   = (const float*)d_in[7];

  char* w = (char*)d_ws;
  short* xb   = (short*)(w + 0);          //  8.0 MB  x bf16 row-major
  short* wqc  = (short*)(w + 8388608);    //  8.0 MB  Wq CHUNK-major
  short* woc  = (short*)(w + 16777216);   //  8.0 MB  Wo CHUNK-major
  short* wvb  = (short*)(w + 25165824);   //  0.5 MB  Wv row-major [128][2048]
  short* vt   = (short*)(w + 25690112);   //  0.5 MB  V^T bf16 [128][2048]
  short* qb   = (short*)(w + 26214400);   //  8.0 MB  Q roped (pre-scaled)
  short* kb   = (short*)(w + 34603008);   //  8.0 MB  K roped
  short* attb = (short*)(w + 42991616);   //  8.0 MB  att bf16
  // partials overlay xb/wqc (dead after QKV GEMMs); pml in fresh space
  float* pO   = (float*)(w + 0);          // 16.78 MB
  float* pml  = (float*)(w + 51380224);   // 512 KB

  cast_all<<<dim3(6272), dim3(256), 0, stream>>>(x, Wq, Wv, Wo, xb, wqc, wvb, woc);

  gemm128<1><<<dim3(256), dim3(1024), 0, stream>>>(xb, wqc, nullptr, qb, kb,
                                                   cosT, sinT, qg);
  gemm64v<<<dim3(32), dim3(256), 0, stream>>>(xb, wvb, vt);
  attn_part<<<dim3(512), dim3(256), 0, stream>>>(qb, kb, vt, attb, pO, pml);
  attn_comb<<<dim3(256), dim3(256), 0, stream>>>(pO, pml, attb);
  gemm128<0><<<dim3(256), dim3(1024), 0, stream>>>(attb, woc, (float*)d_out,
                                                   nullptr, nullptr,
                                                   nullptr, nullptr, nullptr);
}

// Round 18
// 125.744 us; speedup vs baseline: 1.2255x; 1.2255x over previous
//
#include <hip/hip_runtime.h>
#include <hip/hip_bf16.h>

#define SL 2048
#define NH 16
#define HD 128
#define EMB 2048

typedef __attribute__((ext_vector_type(8))) __bf16 bf16x8;
typedef __attribute__((ext_vector_type(4))) float f32x4;
typedef __attribute__((ext_vector_type(8))) short short8;

__device__ __forceinline__ short bf16bits(float x) {
  union { __hip_bfloat16 h; short s; } u;
  u.h = __float2bfloat16(x);
  return u.s;
}

__device__ __forceinline__ float fexp2(float x) {   // native v_exp_f32 (2^x)
  return __builtin_amdgcn_exp2f(x);
}

#define GLDS16(gp, lp) __builtin_amdgcn_global_load_lds( \
    (__attribute__((address_space(1))) void*)(gp), \
    (__attribute__((address_space(3))) void*)(lp), 16, 0, 0)

// ------------------------------------------------ merged cast (x, Wq, Wv, Wo)
__global__ __launch_bounds__(256) void cast_all(const float* __restrict__ x,
                                                const float* __restrict__ Wq,
                                                const float* __restrict__ Wv,
                                                const float* __restrict__ Wo,
                                                short* __restrict__ xb,
                                                short* __restrict__ wqvb,
                                                short* __restrict__ wob) {
  long i = ((long)blockIdx.x * 256 + threadIdx.x) * 8;   // 12845056 elements total
  const float* in; short* out; long off;
  if (i < 4194304)      { in = x;  out = xb;             off = i; }
  else if (i < 8388608) { in = Wq; out = wqvb;           off = i - 4194304; }
  else if (i < 8650752) { in = Wv; out = wqvb + 4194304; off = i - 8388608; }
  else                  { in = Wo; out = wob;            off = i - 8650752; }
  float4 a = *(const float4*)(in + off);
  float4 b = *(const float4*)(in + off + 4);
  short8 o;
  o[0] = bf16bits(a.x); o[1] = bf16bits(a.y); o[2] = bf16bits(a.z); o[3] = bf16bits(a.w);
  o[4] = bf16bits(b.x); o[5] = bf16bits(b.y); o[6] = bf16bits(b.z); o[7] = bf16bits(b.w);
  *(short8*)(out + off) = o;
}

// ------------- 128x128 tile, BK=64, 16-WAVE (1024 thr), 4-deep pipeline NT GEMM
// (r16-proven). MODE 0: C f32, grid 256. MODE 1: fused rmsnorm+rope(Q)+rope(rope(Q)),
// grid 256; Qb PRE-SCALED by 1/sqrt(128)*log2(e) (exp2-domain attn).
template<int MODE>
__global__ __launch_bounds__(1024, 1) void gemm128(const short* __restrict__ A,
                                                   const short* __restrict__ B,
                                                   float* __restrict__ C,
                                                   short* __restrict__ Qb,
                                                   short* __restrict__ Kb,
                                                   const float* __restrict__ cosT,
                                                   const float* __restrict__ sinT,
                                                   const float* __restrict__ gamma) {
  __shared__ char arena[131072];           // 4 bufs x (A 16KB + B 16KB)
  short* As = (short*)arena;
  const int K = 2048;
  int id = blockIdx.x;                      // 256 blocks
  int nid = (id & 7) * 32 + (id >> 3);      // bijective XCD swizzle (256%8==0)
  int tn = nid >> 4, tm = nid & 15;
  int tid = threadIdx.x;
  int w = tid >> 6, lane = tid & 63;
  int g = lane >> 4, c = lane & 15;
  int wr = w >> 2, wc = w & 3;              // 4M x 4N wave grid
  const short* Ab = A + (long)(tm * 128) * K;
  const short* Bb = B + (long)(tn * 128) * K;
  int lr = lane >> 3;                       // row within 8-row stage group
  int lsw = (lane & 7) ^ lr;                // pre-swizzled global chunk for staging
  int wS = w & 7;                           // stage role index
  const short* Sb = (w < 8) ? Ab : Bb;      // waves 0-7: A, 8-15: B
  int soff = (w < 8) ? 0 : 8192;            // dest offset in shorts
  f32x4 zero = {0.f, 0.f, 0.f, 0.f};
  f32x4 acc[2][2];
#pragma unroll
  for (int m = 0; m < 2; ++m)
#pragma unroll
    for (int n = 0; n < 2; ++n) acc[m][n] = zero;

#define STG(buf, kt) do { \
    _Pragma("unroll") \
    for (int j = 0; j < 2; ++j) { \
      int grp = wS * 2 + j; \
      GLDS16(Sb + (long)(grp * 8 + lr) * K + (kt) + lsw * 8, \
             As + (buf) * 16384 + soff + grp * 512); \
    } } while (0)

  STG(0, 0);
  STG(1, 64);
  STG(2, 128);
  asm volatile("s_waitcnt vmcnt(4)" ::: "memory");   // tile 0 landed
  __builtin_amdgcn_s_barrier();

  for (int it = 0; it < 32; ++it) {
    int bf = it & 3;
    if (it < 29) STG((it + 3) & 3, (it + 3) * 64);
    const short* Ax = As + bf * 16384;
    const short* Bx = Ax + 8192;
    bf16x8 af[2][2], bfr[2][2];
#pragma unroll
    for (int kk = 0; kk < 2; ++kk) {
      int ch = ((kk * 4 + g) ^ (c & 7)) * 8;
#pragma unroll
      for (int m = 0; m < 2; ++m)
        af[kk][m] = *(const bf16x8*)(Ax + (wr * 32 + m * 16 + c) * 64 + ch);
#pragma unroll
      for (int n = 0; n < 2; ++n)
        bfr[kk][n] = *(const bf16x8*)(Bx + (wc * 32 + n * 16 + c) * 64 + ch);
    }
    __builtin_amdgcn_s_setprio(1);
#pragma unroll
    for (int kk = 0; kk < 2; ++kk)
#pragma unroll
      for (int m = 0; m < 2; ++m)
#pragma unroll
        for (int n = 0; n < 2; ++n)
          acc[m][n] = __builtin_amdgcn_mfma_f32_16x16x32_bf16(af[kk][m], bfr[kk][n],
                                                              acc[m][n], 0, 0, 0);
    __builtin_amdgcn_s_setprio(0);
    if (it < 29) {
      asm volatile("s_waitcnt vmcnt(4)" ::: "memory");
    } else if (it == 29) {
      asm volatile("s_waitcnt vmcnt(2)" ::: "memory");
    } else if (it == 30) {
      asm volatile("s_waitcnt vmcnt(0)" ::: "memory");
    }
    if (it < 31) __builtin_amdgcn_s_barrier();
  }
#undef STG

  if constexpr (MODE == 0) {
#pragma unroll
    for (int m = 0; m < 2; ++m)
#pragma unroll
      for (int n = 0; n < 2; ++n)
#pragma unroll
        for (int r = 0; r < 4; ++r) {
          int row = tm * 128 + wr * 32 + m * 16 + g * 4 + r;
          int col = tn * 128 + wc * 32 + n * 16 + c;
          C[(long)row * 2048 + col] = acc[m][n][r];
        }
  } else {
    // fused rmsnorm + rope(Q) + rope(rope(Q)); head = tn, d = wc*32+n*16+c.
    float* xch = (float*)arena;             // [128][128] f32 = 64 KB (bufs 0-1)
    float* ssb = (float*)(arena + 65536);   // [4][128] f32 (buf2 head)
    float ssmr[2][4];
#pragma unroll
    for (int m = 0; m < 2; ++m)
#pragma unroll
      for (int r = 0; r < 4; ++r) {
        float s = acc[m][0][r] * acc[m][0][r] + acc[m][1][r] * acc[m][1][r];
#pragma unroll
        for (int off = 1; off <= 8; off <<= 1) s += __shfl_xor(s, off, 64);
        ssmr[m][r] = s;                      // sum over this wave's 32 cols
      }
    if (c == 0) {
#pragma unroll
      for (int m = 0; m < 2; ++m)
#pragma unroll
        for (int r = 0; r < 4; ++r)
          ssb[wc * 128 + wr * 32 + m * 16 + g * 4 + r] = ssmr[m][r];
    }
#pragma unroll
    for (int m = 0; m < 2; ++m)
#pragma unroll
      for (int n = 0; n < 2; ++n)
#pragma unroll
        for (int r = 0; r < 4; ++r)
          xch[(wr * 32 + m * 16 + g * 4 + r) * 128 + wc * 32 + n * 16 + c] = acc[m][n][r];
    __syncthreads();
    float rn[2][4];
#pragma unroll
    for (int m = 0; m < 2; ++m)
#pragma unroll
      for (int r = 0; r < 4; ++r) {
        int rl = wr * 32 + m * 16 + g * 4 + r;
        float s4 = ssb[rl] + ssb[128 + rl] + ssb[256 + rl] + ssb[384 + rl];
        rn[m][r] = rsqrtf(s4 * (1.0f / 128.0f) + 1e-6f);
      }
    float sgn = (wc < 2) ? -1.f : 1.f;
    float g_own[2], g_par[2];
#pragma unroll
    for (int n = 0; n < 2; ++n) {
      int d = wc * 32 + n * 16 + c;
      g_own[n] = gamma[d];
      g_par[n] = gamma[d ^ 64];
    }
    const float QSC = 0.08838834764831845f * 1.4426950408889634f;  // sc * log2(e)
#pragma unroll
    for (int m = 0; m < 2; ++m)
#pragma unroll
      for (int n = 0; n < 2; ++n)
#pragma unroll
        for (int r = 0; r < 4; ++r) {
          int rl = wr * 32 + m * 16 + g * 4 + r;
          int s = tm * 128 + rl;
          int d = wc * 32 + n * 16 + c;
          int u = (wc & 1) * 32 + n * 16 + c;       // d mod 64 (tables 64-periodic)
          float cv = cosT[s * 128 + u];
          float sv = sinT[s * 128 + u];
          float xo = acc[m][n][r] * rn[m][r] * g_own[n];
          float xq = xch[rl * 128 + (d ^ 64)] * rn[m][r] * g_par[n];
          float y  = xo * cv + sgn * xq * sv;       // rope(Q)
          float yp = xq * cv - sgn * xo * sv;       // rope(Q) at partner d
          float kk = y * cv + sgn * yp * sv;        // rope(rope(Q)) (source bug)
          long o = ((long)tn * SL + s) * HD + d;
          Qb[o] = bf16bits(y * QSC);                // pre-scaled for exp2-domain attn
          Kb[o] = bf16bits(kk);                     // K stays unscaled
        }
  }
}

// ----------------------- TRIPLE-buffered NT GEMM 64x128 (r11/r12-proven), V^T only
__global__ __launch_bounds__(256, 3) void gemm64v(const short* __restrict__ A,
                                                  const short* __restrict__ B,
                                                  short* __restrict__ VT) {
  __shared__ char lds_raw[36864];
  short* As = (short*)lds_raw;             // [3][64*32]  12 KB
  short* Bs = (short*)(lds_raw + 12288);   // [3][128*32] 24 KB
  const int K = 2048;
  int nwg = gridDim.x;                          // 32
  int id = blockIdx.x;
  int nid = (id & 7) * (nwg >> 3) + (id >> 3);
  int tn = 16;
  int tm = nid & 31;
  int tid = threadIdx.x;
  int wave = tid >> 6, lane = tid & 63;
  int g = lane >> 4, c = lane & 15;
  int wr = wave >> 1, wc = wave & 1;
  const short* Ab = A + (long)(tm * 64) * K;
  const short* Bb = B + (long)(tn * 128) * K;
  int swz = (lane & 3) ^ ((lane >> 3) & 3);
  int rdc = (g ^ ((c >> 1) & 3)) * 8;
  f32x4 zero = {0.f, 0.f, 0.f, 0.f};
  f32x4 acc[2][4];
#pragma unroll
  for (int m = 0; m < 2; ++m)
#pragma unroll
    for (int n = 0; n < 4; ++n) acc[m][n] = zero;

#define STG(buf, kt) do { \
    GLDS16(Ab + (long)(wave * 16 + (lane >> 2)) * K + (kt) + swz * 8, \
           As + (buf) * 2048 + wave * 512); \
    _Pragma("unroll") \
    for (int hh = 0; hh < 2; ++hh) { \
      int rb = wave * 32 + hh * 16; \
      GLDS16(Bb + (long)(rb + (lane >> 2)) * K + (kt) + swz * 8, \
             Bs + (buf) * 4096 + rb * 32); \
    } } while (0)

  STG(0, 0);
  STG(1, 32);
  asm volatile("s_waitcnt vmcnt(3)" ::: "memory");
  __builtin_amdgcn_s_barrier();

  int b0 = 0, b1 = 1, b2 = 2;
  for (int it = 0; it < 64; ++it) {
    if (it < 62) STG(b2, (it + 2) * 32);
    bf16x8 a[2], b[4];
#pragma unroll
    for (int m = 0; m < 2; ++m)
      a[m] = *(const bf16x8*)(As + b0 * 2048 + (wr * 32 + m * 16 + c) * 32 + rdc);
#pragma unroll
    for (int n = 0; n < 4; ++n)
      b[n] = *(const bf16x8*)(Bs + b0 * 4096 + (wc * 64 + n * 16 + c) * 32 + rdc);
    __builtin_amdgcn_s_setprio(1);
#pragma unroll
    for (int m = 0; m < 2; ++m)
#pragma unroll
      for (int n = 0; n < 4; ++n)
        acc[m][n] = __builtin_amdgcn_mfma_f32_16x16x32_bf16(a[m], b[n], acc[m][n], 0, 0, 0);
    __builtin_amdgcn_s_setprio(0);
    if (it < 62) {
      asm volatile("s_waitcnt vmcnt(3)" ::: "memory");
      __builtin_amdgcn_s_barrier();
    } else if (it == 62) {
      asm volatile("s_waitcnt vmcnt(0)" ::: "memory");
      __builtin_amdgcn_s_barrier();
    }
    int t = b0; b0 = b1; b1 = b2; b2 = t;
  }
#undef STG

#pragma unroll
  for (int m = 0; m < 2; ++m)
#pragma unroll
    for (int n = 0; n < 4; ++n)
#pragma unroll
      for (int r = 0; r < 4; ++r) {
        int s = tm * 64 + wr * 32 + m * 16 + g * 4 + r;
        int d = wc * 64 + n * 16 + c;
        VT[(long)d * SL + s] = bf16bits(acc[m][n][r]);
      }
}

// ------------------------------------------- causal flash attention, k-split chunks
// (r16-proven: head-pinned XCD decode, exp2-domain native, packed b64 Ps stores)
__global__ __launch_bounds__(256, 2) void attn_part(const short* __restrict__ Qb,
                                                    const short* __restrict__ Kb,
                                                    const short* __restrict__ VTg,
                                                    short* __restrict__ att,
                                                    float* __restrict__ pO,
                                                    float* __restrict__ pml) {
  __shared__ short Ks[2][64 * 128];   // 32 KB
  __shared__ short Vs[2][128 * 64];   // 32 KB
  __shared__ short Ps[4][16 * 72];    // 9 KB per-wave
  int wave = threadIdx.x >> 6, lane = threadIdx.x & 63;
  int g = lane >> 4, c = lane & 15;
  int id = blockIdx.x;
  int h = ((id & 7) << 1) | (id >> 8);   // head-pinned XCD decode
  int x = (id >> 3) & 15;
  int cbk = (id >> 7) & 1;
  const short* Qh = Qb + (long)h * SL * HD;
  const short* Kh = Kb + (long)h * SL * HD;
  f32x4 zero = {0.f, 0.f, 0.f, 0.f};
  const float THR2 = 11.541560327111707f;   // 8 * log2(e)

  int pqt[2], plo[2], pcnt[2], pout[2];
  if (cbk == 0) {
    pqt[0] = x;      plo[0] = 0;      pcnt[0] = x + 1;  pout[0] = 0;
    pqt[1] = 31 - x; plo[1] = 0;      pcnt[1] = 16 - x; pout[1] = 1;
  } else {
    pqt[0] = 31 - x; plo[0] = 16 - x; pcnt[0] = 16;     pout[0] = 2;
    pqt[1] = 0;      plo[1] = 0;      pcnt[1] = 0;      pout[1] = 0;
  }
  int total = pcnt[0] + pcnt[1];

#define ASTAGE(b, kvb) do { \
    _Pragma("unroll") \
    for (int i = 0; i < 4; ++i) { \
      int rb = wave * 16 + i * 4; \
      int row = rb + (lane >> 4); \
      int c16 = (lane & 15) ^ (row & 7); \
      GLDS16(Kh + (long)((kvb) + row) * HD + c16 * 8, &Ks[b][rb * 128]); \
    } \
    _Pragma("unroll") \
    for (int i = 0; i < 4; ++i) { \
      int dbase = i * 32 + wave * 8; \
      int drow = dbase + (lane >> 3); \
      int u8 = (lane & 7) ^ (drow & 7); \
      GLDS16(VTg + (long)drow * SL + (kvb) + u8 * 8, &Vs[b][dbase * 64]); \
    } } while (0)

  ASTAGE(0, plo[0] * 64);
  int s = 0;

  for (int p = 0; p < 2; ++p) {
    int nt = pcnt[p];
    if (nt == 0) break;
    int qt = pqt[p];
    int qb = qt * 64 + wave * 16;
    int qown = qb + c;

    bf16x8 aq[4];
#pragma unroll
    for (int kc = 0; kc < 4; ++kc)
      aq[kc] = *(const bf16x8*)(Qh + (long)qown * HD + kc * 32 + g * 8);

    float m = -1e30f, l = 0.f;
    f32x4 O[8];
#pragma unroll
    for (int d8 = 0; d8 < 8; ++d8) O[d8] = zero;

    for (int i = 0; i < nt; ++i, ++s) {
      int kt = plo[p] + i;
      int kvb = kt * 64;
      int bcu = s & 1;
      asm volatile("s_waitcnt vmcnt(0)" ::: "memory");
      __builtin_amdgcn_s_barrier();
      {
        int ns = s + 1;
        if (ns < total) {
          int np = (ns < pcnt[0]) ? 0 : 1;
          int nkt = plo[np] + (ns - (np ? pcnt[0] : 0));
          ASTAGE(bcu ^ 1, nkt * 64);
        }
      }

      f32x4 sf[4];
#pragma unroll
      for (int n = 0; n < 4; ++n) sf[n] = zero;
      __builtin_amdgcn_s_setprio(1);
#pragma unroll
      for (int kc = 0; kc < 4; ++kc)
#pragma unroll
        for (int n = 0; n < 4; ++n) {
          int row = n * 16 + c;
          int u = (kc * 4 + g) ^ (row & 7);
          bf16x8 bk = *(const bf16x8*)(&Ks[bcu][row * 128 + u * 8]);
          sf[n] = __builtin_amdgcn_mfma_f32_16x16x32_bf16(bk, aq[kc], sf[n], 0, 0, 0);
        }
      __builtin_amdgcn_s_setprio(0);

      float pm = -1e30f;
      if (kt == qt) {
#pragma unroll
        for (int n = 0; n < 4; ++n) {
#pragma unroll
          for (int r = 0; r < 4; ++r) {
            int k = kvb + n * 16 + g * 4 + r;
            if (k > qown) sf[n][r] = -1e30f;
          }
          float a0 = fmaxf(sf[n][0], sf[n][1]);
          float a1 = fmaxf(sf[n][2], sf[n][3]);
          pm = fmaxf(pm, fmaxf(a0, a1));
        }
      } else {
#pragma unroll
        for (int n = 0; n < 4; ++n) {
          float a0 = fmaxf(sf[n][0], sf[n][1]);
          float a1 = fmaxf(sf[n][2], sf[n][3]);
          pm = fmaxf(pm, fmaxf(a0, a1));
        }
      }
      pm = fmaxf(pm, __shfl_xor(pm, 16, 64));
      pm = fmaxf(pm, __shfl_xor(pm, 32, 64));

      if (__any(pm > m + THR2)) {
        float mn_ = fmaxf(m, pm);
        float corr = fexp2(m - mn_);
        m = mn_;
        l *= corr;
        float c4[4];
#pragma unroll
        for (int r = 0; r < 4; ++r) c4[r] = __shfl(corr, g * 4 + r, 64);
#pragma unroll
        for (int d8 = 0; d8 < 8; ++d8)
#pragma unroll
          for (int r = 0; r < 4; ++r) O[d8][r] *= c4[r];
      }

#pragma unroll
      for (int n = 0; n < 4; ++n) {
        float p0 = fexp2(sf[n][0] - m);
        float p1 = fexp2(sf[n][1] - m);
        float p2 = fexp2(sf[n][2] - m);
        float p3 = fexp2(sf[n][3] - m);
        l += (p0 + p1) + (p2 + p3);
        unsigned lo = (unsigned)(unsigned short)bf16bits(p0) |
                      ((unsigned)(unsigned short)bf16bits(p1) << 16);
        unsigned hi = (unsigned)(unsigned short)bf16bits(p2) |
                      ((unsigned)(unsigned short)bf16bits(p3) << 16);
        unsigned long long pq = (unsigned long long)lo | ((unsigned long long)hi << 32);
        *(unsigned long long*)&Ps[wave][c * 72 + n * 16 + g * 4] = pq;
      }

#pragma unroll
      for (int k2 = 0; k2 < 2; ++k2) {
        bf16x8 ap = *(const bf16x8*)(&Ps[wave][c * 72 + k2 * 32 + g * 8]);
        __builtin_amdgcn_s_setprio(1);
#pragma unroll
        for (int d8 = 0; d8 < 8; ++d8) {
          int drow = d8 * 16 + c;
          int u = (k2 * 4 + g) ^ (c & 7);
          bf16x8 bv = *(const bf16x8*)(&Vs[bcu][drow * 64 + u * 8]);
          O[d8] = __builtin_amdgcn_mfma_f32_16x16x32_bf16(ap, bv, O[d8], 0, 0, 0);
        }
        __builtin_amdgcn_s_setprio(0);
      }
    }

    if (pout[p] == 0) {
      float lf = l;
      lf += __shfl_xor(lf, 16, 64);
      lf += __shfl_xor(lf, 32, 64);
      float rinv = 1.0f / lf;
      float r4[4];
#pragma unroll
      for (int r = 0; r < 4; ++r) r4[r] = __shfl(rinv, g * 4 + r, 64);
#pragma unroll
      for (int d8 = 0; d8 < 8; ++d8)
#pragma unroll
        for (int r = 0; r < 4; ++r) {
          int q = qb + g * 4 + r;
          att[(long)q * EMB + h * HD + d8 * 16 + c] = bf16bits(O[d8][r] * r4[r]);
        }
    } else {
      int part = pout[p] - 1;
      float lf = l;
      lf += __shfl_xor(lf, 16, 64);
      lf += __shfl_xor(lf, 32, 64);
      float* Op = pO + ((long)(part * 16 + x) * 16 + h) * 8192;
#pragma unroll
      for (int d8 = 0; d8 < 8; ++d8)
#pragma unroll
        for (int r = 0; r < 4; ++r)
          Op[(wave * 16 + g * 4 + r) * 128 + d8 * 16 + c] = O[d8][r];
      if (g == 0) {
        float* pmb = pml + ((part * 16 + x) * 16 + h) * 64 + wave * 16 + c;
        pmb[0]     = m;     // log2-domain running max
        pmb[32768] = lf;
      }
    }
  }
#undef ASTAGE
}

// ------------------------------------------- combine the two partials (long strips)
// m is in log2 domain -> weights use native exp2.
__global__ __launch_bounds__(256) void attn_comb(const float* __restrict__ pO,
                                                 const float* __restrict__ pml,
                                                 short* __restrict__ att) {
  int b = blockIdx.x;
  int x = b & 15, h = b >> 4;
  int qt = 31 - x;
  int t = threadIdx.x;
  int q = t >> 2, d0 = (t & 3) * 32;
  int i0 = (x * 16 + h) * 64 + q;
  int i1 = (256 + x * 16 + h) * 64 + q;
  float m0 = pml[i0], m1 = pml[i1];
  float l0 = pml[32768 + i0], l1 = pml[32768 + i1];
  float M = fmaxf(m0, m1);
  float w0 = __builtin_amdgcn_exp2f(m0 - M), w1 = __builtin_amdgcn_exp2f(m1 - M);
  float inv = 1.0f / (l0 * w0 + l1 * w1);
  const float* O0 = pO + ((long)(x * 16 + h)) * 8192 + q * 128 + d0;
  const float* O1 = pO + ((long)(256 + x * 16 + h)) * 8192 + q * 128 + d0;
  short* out = att + (long)(qt * 64 + q) * EMB + h * HD + d0;
#pragma unroll
  for (int j = 0; j < 32; j += 4) {
    float4 a = *(const float4*)(O0 + j);
    float4 bb = *(const float4*)(O1 + j);
    out[j + 0] = bf16bits((a.x * w0 + bb.x * w1) * inv);
    out[j + 1] = bf16bits((a.y * w0 + bb.y * w1) * inv);
    out[j + 2] = bf16bits((a.z * w0 + bb.z * w1) * inv);
    out[j + 3] = bf16bits((a.w * w0 + bb.w * w1) * inv);
  }
}

// ---------------------------------------------------------------------- launch
extern "C" void kernel_launch(void* const* d_in, const int* in_sizes, int n_in,
                              void* d_out, int out_size, void* d_ws, size_t ws_size,
                              hipStream_t stream) {
  const float* x    = (const float*)d_in[0];
  const float* cosT = (const float*)d_in[1];
  const float* sinT = (const float*)d_in[2];
  const float* Wq   = (const float*)d_in[3];
  const float* Wv   = (const float*)d_in[5];
  const float* Wo   = (const float*)d_in[6];
  const float* qg   = (const float*)d_in[7];

  char* w = (char*)d_ws;
  short* xb   = (short*)(w + 0);          //  8.0 MB  x bf16 [2048][2048]
  short* wqvb = (short*)(w + 8388608);    //  8.5 MB  [Wq;Wv] bf16 [2176][2048]
  short* wob  = (short*)(w + 17301504);   //  8.0 MB  Wo bf16
  short* vt   = (short*)(w + 25690112);   //  0.5 MB  V^T bf16 [128][2048]
  short* qb   = (short*)(w + 26214400);   //  8.0 MB  Q roped bf16 [16][2048][128]
  short* kb   = (short*)(w + 34603008);   //  8.0 MB  K roped bf16 [16][2048][128]
  short* attb = (short*)(w + 42991616);   //  8.0 MB  att bf16 [2048][2048]
  // partials overlay xb/wqvb (dead after the QKV GEMMs):
  float* pO   = (float*)(w + 0);          // 16.78 MB [2part][16x][16h][64][128] f32
  float* pml  = (float*)(w + 16777216);   // 512 KB   m then l

  cast_all<<<dim3(6272), dim3(256), 0, stream>>>(x, Wq, Wv, Wo, xb, wqvb, wob);

  gemm128<1><<<dim3(256), dim3(1024), 0, stream>>>(xb, wqvb, nullptr, qb, kb,
                                                   cosT, sinT, qg);
  gemm64v<<<dim3(32), dim3(256), 0, stream>>>(xb, wqvb, vt);
  attn_part<<<dim3(512), dim3(256), 0, stream>>>(qb, kb, vt, attb, pO, pml);
  attn_comb<<<dim3(256), dim3(256), 0, stream>>>(pO, pml, attb);
  gemm128<0><<<dim3(256), dim3(1024), 0, stream>>>(attb, wob, (float*)d_out,
                                                   nullptr, nullptr,
                                                   nullptr, nullptr, nullptr);
}

// Round 19
// 117.083 us; speedup vs baseline: 1.3161x; 1.0740x over previous
//
#include <hip/hip_runtime.h>
#include <hip/hip_bf16.h>

#define SL 2048
#define NH 16
#define HD 128
#define EMB 2048

typedef __attribute__((ext_vector_type(8))) __bf16 bf16x8;
typedef __attribute__((ext_vector_type(4))) float f32x4;
typedef __attribute__((ext_vector_type(8))) short short8;

__device__ __forceinline__ short bf16bits(float x) {
  union { __hip_bfloat16 h; short s; } u;
  u.h = __float2bfloat16(x);
  return u.s;
}

__device__ __forceinline__ float fexp2(float x) {   // native v_exp_f32 (2^x)
  return __builtin_amdgcn_exp2f(x);
}

#define GLDS16(gp, lp) __builtin_amdgcn_global_load_lds( \
    (__attribute__((address_space(1))) void*)(gp), \
    (__attribute__((address_space(3))) void*)(lp), 16, 0, 0)

// ------------------------------------------------ merged cast (x, Wq, Wv, Wo)
__global__ __launch_bounds__(256) void cast_all(const float* __restrict__ x,
                                                const float* __restrict__ Wq,
                                                const float* __restrict__ Wv,
                                                const float* __restrict__ Wo,
                                                short* __restrict__ xb,
                                                short* __restrict__ wqvb,
                                                short* __restrict__ wob) {
  long i = ((long)blockIdx.x * 256 + threadIdx.x) * 8;   // 12845056 elements total
  const float* in; short* out; long off;
  if (i < 4194304)      { in = x;  out = xb;             off = i; }
  else if (i < 8388608) { in = Wq; out = wqvb;           off = i - 4194304; }
  else if (i < 8650752) { in = Wv; out = wqvb + 4194304; off = i - 8388608; }
  else                  { in = Wo; out = wob;            off = i - 8650752; }
  float4 a = *(const float4*)(in + off);
  float4 b = *(const float4*)(in + off + 4);
  short8 o;
  o[0] = bf16bits(a.x); o[1] = bf16bits(a.y); o[2] = bf16bits(a.z); o[3] = bf16bits(a.w);
  o[4] = bf16bits(b.x); o[5] = bf16bits(b.y); o[6] = bf16bits(b.z); o[7] = bf16bits(b.w);
  *(short8*)(out + off) = o;
}

// ------------- 128x128 tile, BK=64, 16-WAVE (1024 thr), 4-deep pipeline NT GEMM
// (r16-proven, frozen). MODE 0: C f32. MODE 1: fused rmsnorm+rope(Q)+rope(rope(Q));
// Qb PRE-SCALED by 1/sqrt(128)*log2(e) (exp2-domain attn).
template<int MODE>
__global__ __launch_bounds__(1024, 1) void gemm128(const short* __restrict__ A,
                                                   const short* __restrict__ B,
                                                   float* __restrict__ C,
                                                   short* __restrict__ Qb,
                                                   short* __restrict__ Kb,
                                                   const float* __restrict__ cosT,
                                                   const float* __restrict__ sinT,
                                                   const float* __restrict__ gamma) {
  __shared__ char arena[131072];           // 4 bufs x (A 16KB + B 16KB)
  short* As = (short*)arena;
  const int K = 2048;
  int id = blockIdx.x;                      // 256 blocks
  int nid = (id & 7) * 32 + (id >> 3);      // bijective XCD swizzle (256%8==0)
  int tn = nid >> 4, tm = nid & 15;
  int tid = threadIdx.x;
  int w = tid >> 6, lane = tid & 63;
  int g = lane >> 4, c = lane & 15;
  int wr = w >> 2, wc = w & 3;              // 4M x 4N wave grid
  const short* Ab = A + (long)(tm * 128) * K;
  const short* Bb = B + (long)(tn * 128) * K;
  int lr = lane >> 3;                       // row within 8-row stage group
  int lsw = (lane & 7) ^ lr;                // pre-swizzled global chunk for staging
  int wS = w & 7;                           // stage role index
  const short* Sb = (w < 8) ? Ab : Bb;      // waves 0-7: A, 8-15: B
  int soff = (w < 8) ? 0 : 8192;            // dest offset in shorts
  f32x4 zero = {0.f, 0.f, 0.f, 0.f};
  f32x4 acc[2][2];
#pragma unroll
  for (int m = 0; m < 2; ++m)
#pragma unroll
    for (int n = 0; n < 2; ++n) acc[m][n] = zero;

#define STG(buf, kt) do { \
    _Pragma("unroll") \
    for (int j = 0; j < 2; ++j) { \
      int grp = wS * 2 + j; \
      GLDS16(Sb + (long)(grp * 8 + lr) * K + (kt) + lsw * 8, \
             As + (buf) * 16384 + soff + grp * 512); \
    } } while (0)

  STG(0, 0);
  STG(1, 64);
  STG(2, 128);
  asm volatile("s_waitcnt vmcnt(4)" ::: "memory");   // tile 0 landed
  __builtin_amdgcn_s_barrier();

  for (int it = 0; it < 32; ++it) {
    int bf = it & 3;
    if (it < 29) STG((it + 3) & 3, (it + 3) * 64);
    const short* Ax = As + bf * 16384;
    const short* Bx = Ax + 8192;
    bf16x8 af[2][2], bfr[2][2];
#pragma unroll
    for (int kk = 0; kk < 2; ++kk) {
      int ch = ((kk * 4 + g) ^ (c & 7)) * 8;
#pragma unroll
      for (int m = 0; m < 2; ++m)
        af[kk][m] = *(const bf16x8*)(Ax + (wr * 32 + m * 16 + c) * 64 + ch);
#pragma unroll
      for (int n = 0; n < 2; ++n)
        bfr[kk][n] = *(const bf16x8*)(Bx + (wc * 32 + n * 16 + c) * 64 + ch);
    }
    __builtin_amdgcn_s_setprio(1);
#pragma unroll
    for (int kk = 0; kk < 2; ++kk)
#pragma unroll
      for (int m = 0; m < 2; ++m)
#pragma unroll
        for (int n = 0; n < 2; ++n)
          acc[m][n] = __builtin_amdgcn_mfma_f32_16x16x32_bf16(af[kk][m], bfr[kk][n],
                                                              acc[m][n], 0, 0, 0);
    __builtin_amdgcn_s_setprio(0);
    if (it < 29) {
      asm volatile("s_waitcnt vmcnt(4)" ::: "memory");
    } else if (it == 29) {
      asm volatile("s_waitcnt vmcnt(2)" ::: "memory");
    } else if (it == 30) {
      asm volatile("s_waitcnt vmcnt(0)" ::: "memory");
    }
    if (it < 31) __builtin_amdgcn_s_barrier();
  }
#undef STG

  if constexpr (MODE == 0) {
#pragma unroll
    for (int m = 0; m < 2; ++m)
#pragma unroll
      for (int n = 0; n < 2; ++n)
#pragma unroll
        for (int r = 0; r < 4; ++r) {
          int row = tm * 128 + wr * 32 + m * 16 + g * 4 + r;
          int col = tn * 128 + wc * 32 + n * 16 + c;
          C[(long)row * 2048 + col] = acc[m][n][r];
        }
  } else {
    // fused rmsnorm + rope(Q) + rope(rope(Q)); head = tn, d = wc*32+n*16+c.
    float* xch = (float*)arena;             // [128][128] f32 = 64 KB (bufs 0-1)
    float* ssb = (float*)(arena + 65536);   // [4][128] f32 (buf2 head)
    float ssmr[2][4];
#pragma unroll
    for (int m = 0; m < 2; ++m)
#pragma unroll
      for (int r = 0; r < 4; ++r) {
        float s = acc[m][0][r] * acc[m][0][r] + acc[m][1][r] * acc[m][1][r];
#pragma unroll
        for (int off = 1; off <= 8; off <<= 1) s += __shfl_xor(s, off, 64);
        ssmr[m][r] = s;                      // sum over this wave's 32 cols
      }
    if (c == 0) {
#pragma unroll
      for (int m = 0; m < 2; ++m)
#pragma unroll
        for (int r = 0; r < 4; ++r)
          ssb[wc * 128 + wr * 32 + m * 16 + g * 4 + r] = ssmr[m][r];
    }
#pragma unroll
    for (int m = 0; m < 2; ++m)
#pragma unroll
      for (int n = 0; n < 2; ++n)
#pragma unroll
        for (int r = 0; r < 4; ++r)
          xch[(wr * 32 + m * 16 + g * 4 + r) * 128 + wc * 32 + n * 16 + c] = acc[m][n][r];
    __syncthreads();
    float rn[2][4];
#pragma unroll
    for (int m = 0; m < 2; ++m)
#pragma unroll
      for (int r = 0; r < 4; ++r) {
        int rl = wr * 32 + m * 16 + g * 4 + r;
        float s4 = ssb[rl] + ssb[128 + rl] + ssb[256 + rl] + ssb[384 + rl];
        rn[m][r] = rsqrtf(s4 * (1.0f / 128.0f) + 1e-6f);
      }
    float sgn = (wc < 2) ? -1.f : 1.f;
    float g_own[2], g_par[2];
#pragma unroll
    for (int n = 0; n < 2; ++n) {
      int d = wc * 32 + n * 16 + c;
      g_own[n] = gamma[d];
      g_par[n] = gamma[d ^ 64];
    }
    const float QSC = 0.08838834764831845f * 1.4426950408889634f;  // sc * log2(e)
#pragma unroll
    for (int m = 0; m < 2; ++m)
#pragma unroll
      for (int n = 0; n < 2; ++n)
#pragma unroll
        for (int r = 0; r < 4; ++r) {
          int rl = wr * 32 + m * 16 + g * 4 + r;
          int s = tm * 128 + rl;
          int d = wc * 32 + n * 16 + c;
          int u = (wc & 1) * 32 + n * 16 + c;       // d mod 64 (tables 64-periodic)
          float cv = cosT[s * 128 + u];
          float sv = sinT[s * 128 + u];
          float xo = acc[m][n][r] * rn[m][r] * g_own[n];
          float xq = xch[rl * 128 + (d ^ 64)] * rn[m][r] * g_par[n];
          float y  = xo * cv + sgn * xq * sv;       // rope(Q)
          float yp = xq * cv - sgn * xo * sv;       // rope(Q) at partner d
          float kk = y * cv + sgn * yp * sv;        // rope(rope(Q)) (source bug)
          long o = ((long)tn * SL + s) * HD + d;
          Qb[o] = bf16bits(y * QSC);                // pre-scaled for exp2-domain attn
          Kb[o] = bf16bits(kk);                     // K stays unscaled
        }
  }
}

// ------------------- SPLIT-K=8 NT GEMM 64x128 for V (was gemm64v, 32 blocks
// idling 224 CUs for 64 iters). Grid 256 = 8 k-chunks x 32 tiles, 8-iter chains,
// f32 partials -> pv (attb region, dead at this point). comb64v reduces.
__global__ __launch_bounds__(256, 3) void gemm64v_sk(const short* __restrict__ A,
                                                     const short* __restrict__ B,
                                                     float* __restrict__ pv) {
  __shared__ char lds_raw[36864];
  short* As = (short*)lds_raw;             // [3][64*32]  12 KB
  short* Bs = (short*)(lds_raw + 12288);   // [3][128*32] 24 KB
  const int K = 2048;
  int id = blockIdx.x;
  int nid = (id & 7) * 32 + (id >> 3);     // bijective (256%8==0)
  int kc = nid >> 5;                       // k-chunk 0..7
  int tm = nid & 31;
  int k0 = kc * 256;
  int tid = threadIdx.x;
  int wave = tid >> 6, lane = tid & 63;
  int g = lane >> 4, c = lane & 15;
  int wr = wave >> 1, wc = wave & 1;
  const short* Ab = A + (long)(tm * 64) * K;
  const short* Bb = B + (long)(16 * 128) * K;   // Wv rows of wqvb
  int swz = (lane & 3) ^ ((lane >> 3) & 3);
  int rdc = (g ^ ((c >> 1) & 3)) * 8;
  f32x4 zero = {0.f, 0.f, 0.f, 0.f};
  f32x4 acc[2][4];
#pragma unroll
  for (int m = 0; m < 2; ++m)
#pragma unroll
    for (int n = 0; n < 4; ++n) acc[m][n] = zero;

#define STG(buf, kt) do { \
    GLDS16(Ab + (long)(wave * 16 + (lane >> 2)) * K + (kt) + swz * 8, \
           As + (buf) * 2048 + wave * 512); \
    _Pragma("unroll") \
    for (int hh = 0; hh < 2; ++hh) { \
      int rb = wave * 32 + hh * 16; \
      GLDS16(Bb + (long)(rb + (lane >> 2)) * K + (kt) + swz * 8, \
             Bs + (buf) * 4096 + rb * 32); \
    } } while (0)

  STG(0, k0);
  STG(1, k0 + 32);
  asm volatile("s_waitcnt vmcnt(3)" ::: "memory");
  __builtin_amdgcn_s_barrier();

  int b0 = 0, b1 = 1, b2 = 2;
  for (int it = 0; it < 8; ++it) {
    if (it < 6) STG(b2, k0 + (it + 2) * 32);
    bf16x8 a[2], b[4];
#pragma unroll
    for (int m = 0; m < 2; ++m)
      a[m] = *(const bf16x8*)(As + b0 * 2048 + (wr * 32 + m * 16 + c) * 32 + rdc);
#pragma unroll
    for (int n = 0; n < 4; ++n)
      b[n] = *(const bf16x8*)(Bs + b0 * 4096 + (wc * 64 + n * 16 + c) * 32 + rdc);
    __builtin_amdgcn_s_setprio(1);
#pragma unroll
    for (int m = 0; m < 2; ++m)
#pragma unroll
      for (int n = 0; n < 4; ++n)
        acc[m][n] = __builtin_amdgcn_mfma_f32_16x16x32_bf16(a[m], b[n], acc[m][n], 0, 0, 0);
    __builtin_amdgcn_s_setprio(0);
    if (it < 6) {
      asm volatile("s_waitcnt vmcnt(3)" ::: "memory");
      __builtin_amdgcn_s_barrier();
    } else if (it == 6) {
      asm volatile("s_waitcnt vmcnt(0)" ::: "memory");
      __builtin_amdgcn_s_barrier();
    }
    int t = b0; b0 = b1; b1 = b2; b2 = t;
  }
#undef STG

  // f32 partial: pv[kc][s][d]
#pragma unroll
  for (int m = 0; m < 2; ++m)
#pragma unroll
    for (int n = 0; n < 4; ++n)
#pragma unroll
      for (int r = 0; r < 4; ++r) {
        int s = tm * 64 + wr * 32 + m * 16 + g * 4 + r;
        int d = wc * 64 + n * 16 + c;
        pv[(long)kc * 262144 + (long)s * 128 + d] = acc[m][n][r];
      }
}

// ---------------- reduce 8 V partials -> V^T bf16 (LDS transpose for coalescing)
__global__ __launch_bounds__(256) void comb64v(const float* __restrict__ pv,
                                               short* __restrict__ VT) {
  __shared__ float ttile[8][128];
  int b = blockIdx.x;               // s-range [b*8, b*8+8)
  int t = threadIdx.x;
  int d = t & 127, sh = t >> 7;     // 128 d x 2 s-halves
#pragma unroll
  for (int j = 0; j < 4; ++j) {
    int s = b * 8 + sh * 4 + j;
    float sum = 0.f;
#pragma unroll
    for (int kc = 0; kc < 8; ++kc)
      sum += pv[(long)kc * 262144 + (long)s * 128 + d];
    ttile[sh * 4 + j][d] = sum;
  }
  __syncthreads();
  if (t < 128) {
    short8 o;
#pragma unroll
    for (int j = 0; j < 8; ++j) o[j] = bf16bits(ttile[j][t]);
    *(short8*)(VT + (long)t * SL + b * 8) = o;
  }
}

// ------------------------------------------- causal flash attention, k-split chunks
// (r16-proven, frozen: head-pinned XCD decode, exp2-domain native, packed b64 Ps)
__global__ __launch_bounds__(256, 2) void attn_part(const short* __restrict__ Qb,
                                                    const short* __restrict__ Kb,
                                                    const short* __restrict__ VTg,
                                                    short* __restrict__ att,
                                                    float* __restrict__ pO,
                                                    float* __restrict__ pml) {
  __shared__ short Ks[2][64 * 128];   // 32 KB
  __shared__ short Vs[2][128 * 64];   // 32 KB
  __shared__ short Ps[4][16 * 72];    // 9 KB per-wave
  int wave = threadIdx.x >> 6, lane = threadIdx.x & 63;
  int g = lane >> 4, c = lane & 15;
  int id = blockIdx.x;
  int h = ((id & 7) << 1) | (id >> 8);   // head-pinned XCD decode
  int x = (id >> 3) & 15;
  int cbk = (id >> 7) & 1;
  const short* Qh = Qb + (long)h * SL * HD;
  const short* Kh = Kb + (long)h * SL * HD;
  f32x4 zero = {0.f, 0.f, 0.f, 0.f};
  const float THR2 = 11.541560327111707f;   // 8 * log2(e)

  int pqt[2], plo[2], pcnt[2], pout[2];
  if (cbk == 0) {
    pqt[0] = x;      plo[0] = 0;      pcnt[0] = x + 1;  pout[0] = 0;
    pqt[1] = 31 - x; plo[1] = 0;      pcnt[1] = 16 - x; pout[1] = 1;
  } else {
    pqt[0] = 31 - x; plo[0] = 16 - x; pcnt[0] = 16;     pout[0] = 2;
    pqt[1] = 0;      plo[1] = 0;      pcnt[1] = 0;      pout[1] = 0;
  }
  int total = pcnt[0] + pcnt[1];

#define ASTAGE(b, kvb) do { \
    _Pragma("unroll") \
    for (int i = 0; i < 4; ++i) { \
      int rb = wave * 16 + i * 4; \
      int row = rb + (lane >> 4); \
      int c16 = (lane & 15) ^ (row & 7); \
      GLDS16(Kh + (long)((kvb) + row) * HD + c16 * 8, &Ks[b][rb * 128]); \
    } \
    _Pragma("unroll") \
    for (int i = 0; i < 4; ++i) { \
      int dbase = i * 32 + wave * 8; \
      int drow = dbase + (lane >> 3); \
      int u8 = (lane & 7) ^ (drow & 7); \
      GLDS16(VTg + (long)drow * SL + (kvb) + u8 * 8, &Vs[b][dbase * 64]); \
    } } while (0)

  ASTAGE(0, plo[0] * 64);
  int s = 0;

  for (int p = 0; p < 2; ++p) {
    int nt = pcnt[p];
    if (nt == 0) break;
    int qt = pqt[p];
    int qb = qt * 64 + wave * 16;
    int qown = qb + c;

    bf16x8 aq[4];
#pragma unroll
    for (int kc = 0; kc < 4; ++kc)
      aq[kc] = *(const bf16x8*)(Qh + (long)qown * HD + kc * 32 + g * 8);

    float m = -1e30f, l = 0.f;
    f32x4 O[8];
#pragma unroll
    for (int d8 = 0; d8 < 8; ++d8) O[d8] = zero;

    for (int i = 0; i < nt; ++i, ++s) {
      int kt = plo[p] + i;
      int kvb = kt * 64;
      int bcu = s & 1;
      asm volatile("s_waitcnt vmcnt(0)" ::: "memory");
      __builtin_amdgcn_s_barrier();
      {
        int ns = s + 1;
        if (ns < total) {
          int np = (ns < pcnt[0]) ? 0 : 1;
          int nkt = plo[np] + (ns - (np ? pcnt[0] : 0));
          ASTAGE(bcu ^ 1, nkt * 64);
        }
      }

      f32x4 sf[4];
#pragma unroll
      for (int n = 0; n < 4; ++n) sf[n] = zero;
      __builtin_amdgcn_s_setprio(1);
#pragma unroll
      for (int kc = 0; kc < 4; ++kc)
#pragma unroll
        for (int n = 0; n < 4; ++n) {
          int row = n * 16 + c;
          int u = (kc * 4 + g) ^ (row & 7);
          bf16x8 bk = *(const bf16x8*)(&Ks[bcu][row * 128 + u * 8]);
          sf[n] = __builtin_amdgcn_mfma_f32_16x16x32_bf16(bk, aq[kc], sf[n], 0, 0, 0);
        }
      __builtin_amdgcn_s_setprio(0);

      float pm = -1e30f;
      if (kt == qt) {
#pragma unroll
        for (int n = 0; n < 4; ++n) {
#pragma unroll
          for (int r = 0; r < 4; ++r) {
            int k = kvb + n * 16 + g * 4 + r;
            if (k > qown) sf[n][r] = -1e30f;
          }
          float a0 = fmaxf(sf[n][0], sf[n][1]);
          float a1 = fmaxf(sf[n][2], sf[n][3]);
          pm = fmaxf(pm, fmaxf(a0, a1));
        }
      } else {
#pragma unroll
        for (int n = 0; n < 4; ++n) {
          float a0 = fmaxf(sf[n][0], sf[n][1]);
          float a1 = fmaxf(sf[n][2], sf[n][3]);
          pm = fmaxf(pm, fmaxf(a0, a1));
        }
      }
      pm = fmaxf(pm, __shfl_xor(pm, 16, 64));
      pm = fmaxf(pm, __shfl_xor(pm, 32, 64));

      if (__any(pm > m + THR2)) {
        float mn_ = fmaxf(m, pm);
        float corr = fexp2(m - mn_);
        m = mn_;
        l *= corr;
        float c4[4];
#pragma unroll
        for (int r = 0; r < 4; ++r) c4[r] = __shfl(corr, g * 4 + r, 64);
#pragma unroll
        for (int d8 = 0; d8 < 8; ++d8)
#pragma unroll
          for (int r = 0; r < 4; ++r) O[d8][r] *= c4[r];
      }

#pragma unroll
      for (int n = 0; n < 4; ++n) {
        float p0 = fexp2(sf[n][0] - m);
        float p1 = fexp2(sf[n][1] - m);
        float p2 = fexp2(sf[n][2] - m);
        float p3 = fexp2(sf[n][3] - m);
        l += (p0 + p1) + (p2 + p3);
        unsigned lo = (unsigned)(unsigned short)bf16bits(p0) |
                      ((unsigned)(unsigned short)bf16bits(p1) << 16);
        unsigned hi = (unsigned)(unsigned short)bf16bits(p2) |
                      ((unsigned)(unsigned short)bf16bits(p3) << 16);
        unsigned long long pq = (unsigned long long)lo | ((unsigned long long)hi << 32);
        *(unsigned long long*)&Ps[wave][c * 72 + n * 16 + g * 4] = pq;
      }

#pragma unroll
      for (int k2 = 0; k2 < 2; ++k2) {
        bf16x8 ap = *(const bf16x8*)(&Ps[wave][c * 72 + k2 * 32 + g * 8]);
        __builtin_amdgcn_s_setprio(1);
#pragma unroll
        for (int d8 = 0; d8 < 8; ++d8) {
          int drow = d8 * 16 + c;
          int u = (k2 * 4 + g) ^ (c & 7);
          bf16x8 bv = *(const bf16x8*)(&Vs[bcu][drow * 64 + u * 8]);
          O[d8] = __builtin_amdgcn_mfma_f32_16x16x32_bf16(ap, bv, O[d8], 0, 0, 0);
        }
        __builtin_amdgcn_s_setprio(0);
      }
    }

    if (pout[p] == 0) {
      float lf = l;
      lf += __shfl_xor(lf, 16, 64);
      lf += __shfl_xor(lf, 32, 64);
      float rinv = 1.0f / lf;
      float r4[4];
#pragma unroll
      for (int r = 0; r < 4; ++r) r4[r] = __shfl(rinv, g * 4 + r, 64);
#pragma unroll
      for (int d8 = 0; d8 < 8; ++d8)
#pragma unroll
        for (int r = 0; r < 4; ++r) {
          int q = qb + g * 4 + r;
          att[(long)q * EMB + h * HD + d8 * 16 + c] = bf16bits(O[d8][r] * r4[r]);
        }
    } else {
      int part = pout[p] - 1;
      float lf = l;
      lf += __shfl_xor(lf, 16, 64);
      lf += __shfl_xor(lf, 32, 64);
      float* Op = pO + ((long)(part * 16 + x) * 16 + h) * 8192;
#pragma unroll
      for (int d8 = 0; d8 < 8; ++d8)
#pragma unroll
        for (int r = 0; r < 4; ++r)
          Op[(wave * 16 + g * 4 + r) * 128 + d8 * 16 + c] = O[d8][r];
      if (g == 0) {
        float* pmb = pml + ((part * 16 + x) * 16 + h) * 64 + wave * 16 + c;
        pmb[0]     = m;     // log2-domain running max
        pmb[32768] = lf;
      }
    }
  }
#undef ASTAGE
}

// ------------------------------------------- combine the two partials (long strips)
// m is in log2 domain -> weights use native exp2.
__global__ __launch_bounds__(256) void attn_comb(const float* __restrict__ pO,
                                                 const float* __restrict__ pml,
                                                 short* __restrict__ att) {
  int b = blockIdx.x;
  int x = b & 15, h = b >> 4;
  int qt = 31 - x;
  int t = threadIdx.x;
  int q = t >> 2, d0 = (t & 3) * 32;
  int i0 = (x * 16 + h) * 64 + q;
  int i1 = (256 + x * 16 + h) * 64 + q;
  float m0 = pml[i0], m1 = pml[i1];
  float l0 = pml[32768 + i0], l1 = pml[32768 + i1];
  float M = fmaxf(m0, m1);
  float w0 = __builtin_amdgcn_exp2f(m0 - M), w1 = __builtin_amdgcn_exp2f(m1 - M);
  float inv = 1.0f / (l0 * w0 + l1 * w1);
  const float* O0 = pO + ((long)(x * 16 + h)) * 8192 + q * 128 + d0;
  const float* O1 = pO + ((long)(256 + x * 16 + h)) * 8192 + q * 128 + d0;
  short* out = att + (long)(qt * 64 + q) * EMB + h * HD + d0;
#pragma unroll
  for (int j = 0; j < 32; j += 4) {
    float4 a = *(const float4*)(O0 + j);
    float4 bb = *(const float4*)(O1 + j);
    out[j + 0] = bf16bits((a.x * w0 + bb.x * w1) * inv);
    out[j + 1] = bf16bits((a.y * w0 + bb.y * w1) * inv);
    out[j + 2] = bf16bits((a.z * w0 + bb.z * w1) * inv);
    out[j + 3] = bf16bits((a.w * w0 + bb.w * w1) * inv);
  }
}

// ---------------------------------------------------------------------- launch
extern "C" void kernel_launch(void* const* d_in, const int* in_sizes, int n_in,
                              void* d_out, int out_size, void* d_ws, size_t ws_size,
                              hipStream_t stream) {
  const float* x    = (const float*)d_in[0];
  const float* cosT = (const float*)d_in[1];
  const float* sinT = (const float*)d_in[2];
  const float* Wq   = (const float*)d_in[3];
  const float* Wv   = (const float*)d_in[5];
  const float* Wo   = (const float*)d_in[6];
  const float* qg   = (const float*)d_in[7];

  char* w = (char*)d_ws;
  short* xb   = (short*)(w + 0);          //  8.0 MB  x bf16 [2048][2048]
  short* wqvb = (short*)(w + 8388608);    //  8.5 MB  [Wq;Wv] bf16 [2176][2048]
  short* wob  = (short*)(w + 17301504);   //  8.0 MB  Wo bf16
  short* vt   = (short*)(w + 25690112);   //  0.5 MB  V^T bf16 [128][2048]
  short* qb   = (short*)(w + 26214400);   //  8.0 MB  Q roped bf16 [16][2048][128]
  short* kb   = (short*)(w + 34603008);   //  8.0 MB  K roped bf16 [16][2048][128]
  short* attb = (short*)(w + 42991616);   //  8.0 MB  att bf16 [2048][2048]
  // pv (V split-K partials, 8 MB) overlays attb: dead until attn writes att.
  float* pv   = (float*)(w + 42991616);
  // partials overlay xb/wqvb (dead after the QKV GEMMs):
  float* pO   = (float*)(w + 0);          // 16.78 MB [2part][16x][16h][64][128] f32
  float* pml  = (float*)(w + 16777216);   // 512 KB   m then l

  cast_all<<<dim3(6272), dim3(256), 0, stream>>>(x, Wq, Wv, Wo, xb, wqvb, wob);

  gemm128<1><<<dim3(256), dim3(1024), 0, stream>>>(xb, wqvb, nullptr, qb, kb,
                                                   cosT, sinT, qg);
  gemm64v_sk<<<dim3(256), dim3(256), 0, stream>>>(xb, wqvb, pv);
  comb64v<<<dim3(256), dim3(256), 0, stream>>>(pv, vt);
  attn_part<<<dim3(512), dim3(256), 0, stream>>>(qb, kb, vt, attb, pO, pml);
  attn_comb<<<dim3(256), dim3(256), 0, stream>>>(pO, pml, attb);
  gemm128<0><<<dim3(256), dim3(1024), 0, stream>>>(attb, wob, (float*)d_out,
                                                   nullptr, nullptr,
                                                   nullptr, nullptr, nullptr);
}